// Round 4
// baseline (203.094 us; speedup 1.0000x reference)
//
#include <hip/hip_runtime.h>
#include <hip/hip_bf16.h>
#include <math.h>

#define BB   16
#define CIN  256
#define HH   64
#define WW   64
#define COUT 256
#define NEXP 4
#define REDC 16
#define HW   (HH*WW)       // 4096

typedef __attribute__((ext_vector_type(8))) short short8;
typedef __attribute__((ext_vector_type(4))) float f32x4;

#define AS1 __attribute__((address_space(1)))
#define AS3 __attribute__((address_space(3)))

__device__ __forceinline__ void gld_lds16(void* lds, const void* gp) {
    __builtin_amdgcn_global_load_lds((const AS1 unsigned int*)gp,
                                     (AS3 unsigned int*)lds, 16, 0, 0);
}

// -------- K0: x (f32, [b][c][s]) -> xT (bf16, [b][s][c]) + pooled partials --------
__global__ __launch_bounds__(256)
void transpose_pool_kernel(const float* __restrict__ x, ushort* __restrict__ xT,
                           float* __restrict__ pp) {
    int blk = blockIdx.x;
    int sq = blk & 3;
    int chunk = (blk >> 2) & 7;
    int b = blk >> 5;
    int c0 = chunk * 32;
    int s0 = sq * 1024;
    int tid = threadIdx.x;
    const float* xb = x + ((size_t)(b * CIN + c0)) * HW;
    ushort* xTb = xT + (size_t)b * HW * CIN;

    float psum[32];
    #pragma unroll
    for (int i = 0; i < 32; ++i) psum[i] = 0.f;

    for (int it = 0; it < 4; ++it) {
        int s = s0 + it * 256 + tid;
        unsigned int pk[16];
        #pragma unroll
        for (int p = 0; p < 16; ++p) {
            float lo = xb[(size_t)(2 * p) * HW + s];
            float hi = xb[(size_t)(2 * p + 1) * HW + s];
            psum[2 * p]     += lo;
            psum[2 * p + 1] += hi;
            asm volatile("v_cvt_pk_bf16_f32 %0, %1, %2" : "=v"(pk[p]) : "v"(lo), "v"(hi));
        }
        uint4* dst = (uint4*)(xTb + (size_t)s * CIN + c0);
        #pragma unroll
        for (int q = 0; q < 4; ++q)
            dst[q] = make_uint4(pk[q * 4], pk[q * 4 + 1], pk[q * 4 + 2], pk[q * 4 + 3]);
    }

    __shared__ float red[4][32];
    int lane = tid & 63, wid = tid >> 6;
    #pragma unroll
    for (int i = 0; i < 32; ++i) {
        float v = psum[i];
        #pragma unroll
        for (int off = 32; off > 0; off >>= 1) v += __shfl_down(v, off, 64);
        if (lane == 0) red[wid][i] = v;
    }
    __syncthreads();
    if (tid < 32)
        pp[(b * 4 + sq) * 256 + c0 + tid] = red[0][tid] + red[1][tid] + red[2][tid] + red[3][tid];
}

// ---------------- K2: routing MLP -> rw[b*1024 + k*256 + c] ----------------
__global__ void route_kernel(const float* __restrict__ pp,
                             const float* __restrict__ w1, const float* __restrict__ b1,
                             const float* __restrict__ w2, const float* __restrict__ b2,
                             float* __restrict__ rw) {
    __shared__ float p_s[BB][CIN];
    __shared__ float r_s[BB][REDC];
    int tid = threadIdx.x;
    for (int i = tid; i < BB * CIN; i += 256) {
        int b = i >> 8, c = i & 255;
        p_s[b][c] = (pp[(b * 4 + 0) * 256 + c] + pp[(b * 4 + 1) * 256 + c] +
                     pp[(b * 4 + 2) * 256 + c] + pp[(b * 4 + 3) * 256 + c]) * (1.0f / HW);
    }
    __syncthreads();
    {
        int b = tid >> 4, j = tid & 15;
        float acc = b1[j];
        for (int c = 0; c < CIN; ++c) acc += p_s[b][c] * w1[j * CIN + c];
        r_s[b][j] = fmaxf(acc, 0.f);
    }
    __syncthreads();
    for (int i = tid; i < BB * NEXP * CIN; i += 256) {
        int b = i >> 10, o2 = i & 1023;
        float acc = b2[o2];
        #pragma unroll
        for (int j = 0; j < REDC; ++j) acc += r_s[b][j] * w2[o2 * REDC + j];
        rw[i] = 1.f / (1.f + expf(-acc));
    }
}

// ------- K3: combined weights in MFMA fragment layout, bf16 -------
__global__ void combine_kernel(const float* __restrict__ rw,
                               const float* __restrict__ weight,
                               ushort* __restrict__ cw) {
    int cb = blockIdx.x;          // 288 blocks = (ot 4) x (chunk 8) x (t9 9)
    int t9 = cb % 9;
    int tmp = cb / 9;
    int chunk = tmp & 7;
    int ot = tmp >> 3;
    __shared__ float rw_s[BB][NEXP][32];
    int tid = threadIdx.x;
    for (int i = tid; i < BB * NEXP * 32; i += 256) {
        int b = i >> 7, r = i & 127, k = r >> 5, cc = r & 31;
        rw_s[b][k][cc] = rw[b * 1024 + k * 256 + chunk * 32 + cc];
    }
    __syncthreads();
    for (int h = 0; h < 2; ++h) {
        int t = h * 256 + tid;            // 0..511 = o_loc*8 + c8
        int o_loc = t >> 3, c8 = t & 7;
        int o = ot * 64 + o_loc;
        #pragma unroll
        for (int g = 0; g < 4; ++g) {
            int c = chunk * 32 + g * 8 + c8;
            int cl = g * 8 + c8;
            float w0 = weight[((size_t)(0 * COUT + o) * CIN + c) * 9 + t9];
            float w1 = weight[((size_t)(1 * COUT + o) * CIN + c) * 9 + t9];
            float w2 = weight[((size_t)(2 * COUT + o) * CIN + c) * 9 + t9];
            float w3 = weight[((size_t)(3 * COUT + o) * CIN + c) * 9 + t9];
            for (int b = 0; b < BB; ++b) {
                float acc = rw_s[b][0][cl] * w0 + rw_s[b][1][cl] * w1 +
                            rw_s[b][2][cl] * w2 + rw_s[b][3][cl] * w3;
                __hip_bfloat16 hv = __float2bfloat16(acc);
                size_t idx = (((size_t)((b * 4 + ot) * 8 + chunk) * 9 + t9) * 4 + g) * 512 + t;
                cw[idx] = *(ushort*)&hv;
            }
        }
    }
}

// -------- stage one chunk into LDS buffer (19 gld_lds16 per wave) --------
__device__ __forceinline__ void stage_tile(unsigned int* xsb, unsigned int* asb,
                                           const ushort* xTb, const ushort* Ac,
                                           const ushort* zp, int r0, int lane,
                                           int wid, int chunk) {
    #pragma unroll
    for (int k2 = 0; k2 < 9; ++k2) {
        int blk16 = k2 * 4 + wid;
        gld_lds16(&asb[blk16 * 256],
                  (const char*)Ac + (size_t)blk16 * 1024 + lane * 16);
    }
    #pragma unroll
    for (int r = 0; r < 10; ++r) {
        int grow = r0 - 1 + r;
        int sbase = r * 66 + 1 + wid * 16;
        int s_l = sbase + (lane >> 2);
        int sigma = (lane & 3) ^ ((s_l >> 1) & 3);
        const ushort* src = xTb
            + (size_t)((long)grow * 64 + wid * 16 + (lane >> 2)) * CIN
            + chunk * 32 + sigma * 8;
        if (grow < 0 || grow > 63) src = zp + lane * 8;   // block-uniform select
        gld_lds16(&xsb[sbase * 16], src);
    }
}

// ---------------- K4: MFMA implicit-GEMM conv, double-buffered pipeline ----------------
// block: 256 thr (4 waves), 1 block/CU (158 KB LDS). T3/T4: raw s_barrier +
// counted vmcnt(19) keeps next chunk's global_load_lds in flight under MFMA.
__global__ __launch_bounds__(256, 1)
void conv_mfma(const ushort* __restrict__ xT, const ushort* __restrict__ cw,
               float* __restrict__ out, const ushort* __restrict__ zp) {
    __shared__ unsigned int xs[2][10560];   // 2 x 42240 B
    __shared__ unsigned int as[2][9216];    // 2 x 36864 B

    int hw = blockIdx.x;
    int L = (hw & 7) * 64 + (hw >> 3);   // XCD-chunked swizzle (512 = 8*64)
    int b  = L >> 5;
    int rt = (L >> 2) & 7;
    int ot = L & 3;
    int r0 = rt * 8, o0 = ot * 64;
    int tid  = threadIdx.x;
    int lane = tid & 63, wid = tid >> 6;
    int l15  = lane & 15, g = lane >> 4;

    // zero both x buffers (halo columns must stay 0)
    unsigned int* xz = &xs[0][0];
    for (int i = tid; i < 2 * 10560; i += 256) xz[i] = 0;

    f32x4 acc[4][8];
    #pragma unroll
    for (int mi = 0; mi < 4; ++mi)
        #pragma unroll
        for (int f = 0; f < 8; ++f) acc[mi][f] = (f32x4)0.f;

    const ushort* xTb = xT + (size_t)b * HW * CIN;
    const ushort* Ab  = cw + (size_t)((b * 4 + ot) * 8) * 18432;

    asm volatile("s_waitcnt lgkmcnt(0)" ::: "memory");
    __builtin_amdgcn_s_barrier();
    __builtin_amdgcn_sched_barrier(0);

    // prologue: stage chunk 0 into buffer 0
    stage_tile(&xs[0][0], &as[0][0], xTb, Ab, zp, r0, lane, wid, 0);

    #pragma unroll 1
    for (int chunk = 0; chunk < 8; ++chunk) {
        int cur = chunk & 1;
        if (chunk < 7) {
            stage_tile(&xs[cur ^ 1][0], &as[cur ^ 1][0], xTb,
                       Ab + (size_t)(chunk + 1) * 18432, zp, r0, lane, wid, chunk + 1);
            asm volatile("s_waitcnt vmcnt(19)" ::: "memory");
        } else {
            asm volatile("s_waitcnt vmcnt(0)" ::: "memory");
        }
        __builtin_amdgcn_s_barrier();
        __builtin_amdgcn_sched_barrier(0);

        const unsigned int* xsb = &xs[cur][0];
        const unsigned int* asb = &as[cur][0];
        int wrow = wid * 2;
        #pragma unroll
        for (int t9 = 0; t9 < 9; ++t9) {
            int di = t9 / 3, dj = t9 - di * 3;
            int abase = (t9 * 4 + g) * 256 + l15 * 4;
            short8 a0 = *(short8*)&asb[abase + 0 * 64];
            short8 a1 = *(short8*)&asb[abase + 1 * 64];
            short8 a2 = *(short8*)&asb[abase + 2 * 64];
            short8 a3 = *(short8*)&asb[abase + 3 * 64];
            #pragma unroll
            for (int f = 0; f < 8; ++f) {
                int s = (wrow + (f >> 2) + di) * 66 + (f & 3) * 16 + l15 + dj;
                short8 bb = *(short8*)&xsb[s * 16 + ((g ^ ((s >> 1) & 3)) << 2)];
                acc[0][f] = __builtin_amdgcn_mfma_f32_16x16x32_bf16(a0, bb, acc[0][f], 0, 0, 0);
                acc[1][f] = __builtin_amdgcn_mfma_f32_16x16x32_bf16(a1, bb, acc[1][f], 0, 0, 0);
                acc[2][f] = __builtin_amdgcn_mfma_f32_16x16x32_bf16(a2, bb, acc[2][f], 0, 0, 0);
                acc[3][f] = __builtin_amdgcn_mfma_f32_16x16x32_bf16(a3, bb, acc[3][f], 0, 0, 0);
            }
        }
        __builtin_amdgcn_sched_barrier(0);
        __builtin_amdgcn_s_barrier();   // all waves done reading buf cur
    }

    // ---- epilogue ----
    #pragma unroll
    for (int mi = 0; mi < 4; ++mi) {
        #pragma unroll
        for (int f = 0; f < 8; ++f) {
            int pos = (r0 + wid * 2 + (f >> 2)) * 64 + (f & 3) * 16 + l15;
            float* op = out + ((size_t)(b * COUT + o0 + mi * 16 + g * 4)) * HW + pos;
            #pragma unroll
            for (int j = 0; j < 4; ++j) op[(size_t)j * HW] = acc[mi][f][j];
        }
    }
}

extern "C" void kernel_launch(void* const* d_in, const int* in_sizes, int n_in,
                              void* d_out, int out_size, void* d_ws, size_t ws_size,
                              hipStream_t stream) {
    const float* x      = (const float*)d_in[0];
    const float* w1     = (const float*)d_in[1];
    const float* b1     = (const float*)d_in[2];
    const float* w2     = (const float*)d_in[3];
    const float* b2     = (const float*)d_in[4];
    const float* weight = (const float*)d_in[5];
    float* out = (float*)d_out;

    float*  ws = (float*)d_ws;
    float*  pp = ws;                              // 16384 f
    float*  rw = ws + 16384;                      // 16384 f
    ushort* cw = (ushort*)(ws + 32768);           // 9437184 ushort (~18.9 MB)
    ushort* xT = (ushort*)(ws + 32768 + 4718592); // 16777216 ushort (~33.6 MB)
    ushort* zp = xT + 16777216;                   // 512 ushort zero page (1 KB)

    hipMemsetAsync(zp, 0, 1024, stream);
    transpose_pool_kernel<<<512, 256, 0, stream>>>(x, xT, pp);
    route_kernel<<<1, 256, 0, stream>>>(pp, w1, b1, w2, b2, rw);
    combine_kernel<<<288, 256, 0, stream>>>(rw, weight, cw);
    conv_mfma<<<512, 256, 0, stream>>>(xT, cw, out, zp);
}